// Round 11
// baseline (603.032 us; speedup 1.0000x reference)
//
#include <hip/hip_runtime.h>
#include <cstdint>

#define EPS 1e-5
typedef unsigned long long u64;
typedef unsigned int u32;
typedef unsigned short u16;
typedef int v4i __attribute__((ext_vector_type(4)));

struct BnArgs { const float *g[6], *b[6], *m[6], *v[6]; };
struct PackArgs { const float* w[5]; u64* wbt[5]; };

// ---------------------------------------------------------------------------
// Fused BN prep: offsets {0,128,256,512,768,1280}, total 1792.
// ---------------------------------------------------------------------------
__global__ void bn_prep_all(BnArgs p, double* __restrict__ scale_all,
                            double* __restrict__ shift_all) {
    int i = blockIdx.x * 256 + threadIdx.x;
    if (i >= 1792) return;
    int l, base;
    if (i < 128)       { l = 0; base = 0; }
    else if (i < 256)  { l = 1; base = 128; }
    else if (i < 512)  { l = 2; base = 256; }
    else if (i < 768)  { l = 3; base = 512; }
    else if (i < 1280) { l = 4; base = 768; }
    else               { l = 5; base = 1280; }
    const int c = i - base;
    double inv = (double)p.g[l][c] / sqrt((double)p.v[l][c] + EPS);
    scale_all[i] = inv;
    shift_all[i] = (double)p.b[l][c] - (double)p.m[l][c] * inv;
}

__global__ void zero_out(float* __restrict__ out, int n) {
    int i = blockIdx.x * blockDim.x + threadIdx.x;
    if (i < n) out[i] = 0.f;
}

// grid-stride u64 zero (borders of padded bit tensors)
__global__ void zero_u64(u64* __restrict__ p, size_t n) {
    size_t i = (size_t)blockIdx.x * 256 + threadIdx.x;
    const size_t step = (size_t)gridDim.x * 256;
    for (; i < n; i += step) p[i] = 0ull;
}

// ---------------------------------------------------------------------------
// Fused weight pack, tap-major: wbt[(tap*OTOT + o)*W64 + w]. A = alpha*scale.
// Emits the exact edge-correction table AND exact integer thresholds
// (Tlt, Tgt) per filter; for layer 4 (L5) also emits +-1 i8 weights for MFMA.
// ---------------------------------------------------------------------------
__global__ void pack_all(PackArgs pk, const double* __restrict__ scale_all,
                         const double* __restrict__ shift_all,
                         double* __restrict__ A_all,
                         int* __restrict__ tlt_all, int* __restrict__ tgt_all,
                         u32* __restrict__ ct_all, signed char* __restrict__ wi8) {
    const int ob = blockIdx.x;
    const int t = threadIdx.x;
    int l, base, Cin, bnoff, OTOT, ctoff;
    if (ob < 128)       { l = 0; base = 0;    Cin = 128; bnoff = 128;  OTOT = 128; ctoff = 0; }
    else if (ob < 384)  { l = 1; base = 128;  Cin = 128; bnoff = 256;  OTOT = 256; ctoff = 2048; }
    else if (ob < 640)  { l = 2; base = 384;  Cin = 256; bnoff = 512;  OTOT = 256; ctoff = 6144; }
    else if (ob < 1152) { l = 3; base = 640;  Cin = 256; bnoff = 768;  OTOT = 512; ctoff = 10240; }
    else                { l = 4; base = 1152; Cin = 512; bnoff = 1280; OTOT = 512; ctoff = 18432; }
    const int o = ob - base;
    const float* wo = pk.w[l] + (size_t)o * Cin * 9;

    double s = 0.0;
    for (int k = t; k < Cin * 9; k += 256) s += fabs((double)wo[k]);
    __shared__ double red[256];
    __shared__ u32 stp[9];
    red[t] = s;
    if (t < 9) stp[t] = 0;
    __syncthreads();
    for (int r = 128; r > 0; r >>= 1) {
        if (t < r) red[t] += red[t + r];
        __syncthreads();
    }
    if (t == 0) {
        double alpha = red[0] / (double)(Cin * 9);
        const double dA = alpha * scale_all[bnoff + o];
        const double dB = shift_all[bnoff + o];
        A_all[ob] = dA;
        const int INF = 1 << 30;
        int Tlt, Tgt = INF;
        if (dA > 0.0) {
            const double tt = -dB / dA;
            if (!(fabs(tt) < 6000.0)) {
                Tlt = (dB < 0.0) ? INF : -INF;
            } else {
                int v0 = (int)floor(tt) - 4;
                int c = INF;
                for (int v = v0; v < v0 + 9; ++v)
                    if (fma(dA, (double)v, dB) >= 0.0) { c = v; break; }
                Tlt = c;
            }
        } else if (dA < 0.0) {
            const double tt = -dB / dA;
            if (!(fabs(tt) < 6000.0)) {
                Tlt = (dB < 0.0) ? INF : -INF;
            } else {
                int v0 = (int)floor(tt) - 4;
                int c = INF;
                for (int v = v0; v < v0 + 9; ++v)
                    if (fma(dA, (double)v, dB) < 0.0) { c = v; break; }
                Tlt = -INF;
                Tgt = (c == INF) ? INF : (c - 1);
            }
        } else {
            Tlt = (dB < 0.0) ? INF : -INF;
        }
        tlt_all[ob] = Tlt;
        tgt_all[ob] = Tgt;
    }

    const int W64 = Cin / 64;
    u64* wbt = pk.wbt[l];
    for (int e = t; e < 9 * W64; e += 256) {
        int tap = e / W64, word = e % W64;
        u64 bits = 0;
        for (int j = 0; j < 64; ++j) {
            int c = word * 64 + j;
            if (wo[c * 9 + tap] < 0.f) bits |= (1ull << j);
        }
        wbt[((size_t)tap * OTOT + o) * W64 + word] = bits;
        atomicAdd(&stp[tap], (u32)__popcll(bits));
    }
    // i8 weights for the L5 MFMA path (exact: +1 / -1, same w<0 convention)
    if (l == 4) {
        for (int e = t; e < 9 * 512; e += 256) {
            const int tap = e / 512, c = e % 512;
            wi8[((size_t)tap * 512 + o) * 512 + c] =
                (wo[c * 9 + tap] < 0.f) ? (signed char)-1 : (signed char)1;
        }
    }
    __syncthreads();

    if (t < 16) {
        const int pat = t;
        int nv = 0;
        u32 cor = 0;
#pragma unroll
        for (int tap = 0; tap < 9; ++tap) {
            const int dy = tap / 3, dx = tap % 3;
            const bool inv = ((pat & 1) && dy == 0) || ((pat & 2) && dy == 2) ||
                             ((pat & 4) && dx == 0) || ((pat & 8) && dx == 2);
            if (inv) cor += stp[tap]; else nv++;
        }
        ct_all[ctoff + pat * OTOT + o] = (u32)(nv * 64 * W64) + 2u * cor;
    }
}

// ---------------------------------------------------------------------------
// conv0 (f64 exact), lane = pixel -> PADDED bits0 [n][34][34][2].
// (round-3/7 measured-best form: LDS-staged weights)
// ---------------------------------------------------------------------------
__global__ __launch_bounds__(256) void conv0_pack(
        const float* __restrict__ x, const float* __restrict__ w0,
        const double* __restrict__ scale, const double* __restrict__ shift,
        u64* __restrict__ bits0) {
    __shared__ double wlds[128 * 27];
    __shared__ double sc[128], sh[128];
    const int tid = threadIdx.x;
    for (int e = tid; e < 128 * 27; e += 256) wlds[e] = (double)w0[e];
    for (int e = tid; e < 128; e += 256) { sc[e] = scale[e]; sh[e] = shift[e]; }
    __syncthreads();

    const int n = blockIdx.y;
    const int p = blockIdx.x * 256 + tid;
    const int y = p >> 5, xx = p & 31;
    const float* xn = x + (size_t)n * 3 * 32 * 32;

    double win[27];
#pragma unroll
    for (int c = 0; c < 3; ++c)
#pragma unroll
        for (int dy = 0; dy < 3; ++dy)
#pragma unroll
            for (int dx = 0; dx < 3; ++dx) {
                const int yy = y + dy - 1, xs = xx + dx - 1;
                const bool ok = (yy >= 0 && yy < 32 && xs >= 0 && xs < 32);
                win[(c * 3 + dy) * 3 + dx] = ok ? (double)xn[(c * 32 + yy) * 32 + xs] : 0.0;
            }

    u64* op = bits0 + (((size_t)n * 34 + (y + 1)) * 34 + (xx + 1)) * 2;
#pragma unroll
    for (int og = 0; og < 2; ++og) {
        u64 word = 0;
#pragma unroll 2
        for (int j = 0; j < 64; ++j) {
            const int o = og * 64 + j;
            const double* wo = &wlds[o * 27];
            double acc = 0.0;
#pragma unroll
            for (int k = 0; k < 27; ++k) acc = fma(wo[k], win[k], acc);
            const double val = acc * sc[o] + sh[o];
            word |= (u64)(val < 0.0) << j;
        }
        op[og] = word;
    }
}

// ---------------------------------------------------------------------------
// bconv7 (L1-L4, unchanged 558us measured-best): xor+__popcll, scalar-weight
// s_load path, integer-threshold epilogue.
// ---------------------------------------------------------------------------
template<int H, int W, int W64, int OTOT, int OPW, bool POOL, bool LAST, int MINW>
__global__ __launch_bounds__(256, MINW) void bconv7(
        const u64* __restrict__ in_bits, const u64* __restrict__ wbt,
        const double* __restrict__ A, const double* __restrict__ B,
        const int* __restrict__ tlt, const int* __restrict__ tgt,
        const u32* __restrict__ ct_all, int ctoff,
        u32* __restrict__ out_bits, float* __restrict__ h5) {
    const int tid = threadIdx.x;
    const int wave = tid >> 6, lane = tid & 63;
    constexpr int WPI = (H * W) / 64;
    const int img = (WPI >= 4) ? blockIdx.z : (blockIdx.z * 4 + wave);
    const int wii = (WPI >= 4) ? (blockIdx.y * 4 + wave) : 0;
    const int y = wii * (64 / W) + lane / W;
    const int x = lane % W;
    const int obase = blockIdx.x * OPW;

    __shared__ u32 ctl[16 * (OPW + 1)];
    for (int e = tid; e < 16 * OPW; e += 256) {
        const int pat = e / OPW, oc = e % OPW;
        ctl[pat * (OPW + 1) + oc] = ct_all[ctoff + pat * OTOT + obase + oc];
    }
    __syncthreads();

    constexpr int RC = W + 2;
    const u64* ib = in_bits + (size_t)img * (H + 2) * RC * W64;

    int acc[OPW];
#pragma unroll
    for (int oc = 0; oc < OPW; ++oc) acc[oc] = 0;

#pragma unroll 1
    for (int dy = 0; dy < 3; ++dy) {
#pragma unroll 1
        for (int dx = 0; dx < 3; ++dx) {
            const u64* q = ib + ((size_t)(y + dy) * RC + (x + dx)) * W64;
            u64 wn[W64];
#pragma unroll
            for (int k = 0; k < W64; ++k) wn[k] = q[k];
            const u64* wt = wbt + (size_t)((dy * 3 + dx) * OTOT + obase) * W64;
#pragma unroll
            for (int oc = 0; oc < OPW; ++oc) {
#pragma unroll
                for (int k = 0; k < W64; ++k)
                    acc[oc] += (int)__popcll(wn[k] ^ wt[oc * W64 + k]);
            }
        }
    }

    const int pat = (y == 0 ? 1 : 0) | (y == H - 1 ? 2 : 0) |
                    (x == 0 ? 4 : 0) | (x == W - 1 ? 8 : 0);
    const int ctbase = pat * (OPW + 1);
    constexpr int Hp = POOL ? H / 2 : H, Wp = POOL ? W / 2 : W;
    const bool writer = (!POOL) || (((lane & 1) == 0) && ((lane & W) == 0));
    const int py = POOL ? (y >> 1) : y, px = POOL ? (x >> 1) : x;

    u32 cur = 0;
#pragma unroll
    for (int oc = 0; oc < OPW; ++oc) {
        int v = (int)ctl[ctbase + oc] - 2 * acc[oc];
        if (POOL) {
            int v2 = max(v, __shfl_xor(v, 1, 64));
            v = max(v2, __shfl_xor(v2, W, 64));
        }
        if (LAST) {
            const double t = fma(A[obase + oc], (double)v, B[obase + oc]);
            const double hcl = fmin(1.0, fmax(-1.0, t));
            if (writer)
                h5[(((size_t)img * OTOT + obase + oc) * Hp + py) * Wp + px] = (float)hcl;
        } else {
            const bool bit = (v < tlt[obase + oc]) | (v > tgt[obase + oc]);
            cur |= (u32)bit << oc;
        }
    }
    if (!LAST && writer) {
        const size_t wordIdx =
            (((size_t)img * (Hp + 2) + (py + 1)) * (Wp + 2) + (px + 1)) * (OTOT / 32)
            + (obase >> 5);
        if (OPW == 32) {
            out_bits[wordIdx] = cur;
        } else {
            u16* o16 = (u16*)out_bits;
            o16[wordIdx * 2 + ((obase >> 4) & 1)] = (u16)cur;
        }
    }
}

// ---------------------------------------------------------------------------
// L5 via MFMA i8 (512->512, 8x8, pool, htanh -> h5). EXACT (r10-verified:
// absmax 0.0). THIS ROUND: software-pipelined double-buffered loads
// (afA/bfA <-> afB/bfB, statically indexed -> registers) so each wave's MFMA
// hides its own L2 weight-load latency; oc split 256->128 per block
// (grid 1024, 12 waves/CU vs 8). Per wave: 4 M-tiles x 2 N-tiles,
// 72 flattened (tap,kg) iterations of mfma_i32_16x16x64_i8.
// Fragment layouts as r10 (m89-verified C/D). Pool: in-lane reg pairs +
// shfl_xor(32). Activations unpacked to LDS i8 [100][528] once per block.
// ---------------------------------------------------------------------------
__global__ __launch_bounds__(256, 3) void bconv5_mfma(
        const u64* __restrict__ bits4, const signed char* __restrict__ wi8,
        const double* __restrict__ A, const double* __restrict__ B,
        float* __restrict__ h5) {
    const int tid = threadIdx.x;
    const int wave = tid >> 6, lane = tid & 63;
    const int img = blockIdx.y;
    const int ntb = blockIdx.x * 8 + wave * 2;      // N-tile base (2 tiles/wave)

    __shared__ __align__(16) signed char act[100 * 528];
    {
        u32* a32 = (u32*)act;
        for (int e = tid; e < 100 * 132; e += 256) a32[e] = 0;
        __syncthreads();
        for (int e = tid; e < 64 * 128; e += 256) {
            const int px = e >> 7, wi = e & 127;
            const int cell = (px >> 3) * 10 + (px & 7) + 11;   // (y+1)*10+(x+1)
            const u64 bb = bits4[((size_t)img * 100 + cell) * 8 + (wi >> 4)];
            const u32 nib = (u32)(bb >> ((wi & 15) * 4)) & 0xF;
            const u32 spread = (nib & 1) | ((nib & 2) << 7) |
                               ((nib & 4) << 14) | ((nib & 8) << 21);
            a32[cell * 132 + wi] = 0x01010101u + 254u * spread;
        }
    }
    __syncthreads();

    const int r16 = lane & 15, kg4 = lane >> 4;
    const int klane = kg4 * 16;                     // per-lane k offset

    int acell[4];
#pragma unroll
    for (int m = 0; m < 4; ++m)
        acell[m] = (m * 2 + (r16 >> 3)) * 10 + (r16 & 7);   // y*10+x (padded grid)

    // per-lane weight row base for q=0: oc = ntb*16 + r16
    const signed char* wbL = wi8 + (size_t)ntb * 8192 + (size_t)r16 * 512;

    v4i acc[4][2];
#pragma unroll
    for (int m = 0; m < 4; ++m)
#pragma unroll
        for (int q = 0; q < 2; ++q) acc[m][q] = (v4i){0, 0, 0, 0};

    auto loadA = [&](int it, v4i* af) {
        const int tap = it >> 3, kg = it & 7;
        const int t3 = (tap * 11) >> 5;             // tap/3 (mul-shift)
        const int coff = t3 * 10 + (tap - t3 * 3);
        const int kofs = kg * 64 + klane;
#pragma unroll
        for (int m = 0; m < 4; ++m)
            af[m] = *(const v4i*)&act[(acell[m] + coff) * 528 + kofs];
    };
    auto loadB = [&](int it, v4i* bf) {
        const int tap = it >> 3, kg = it & 7;
        const size_t base = (size_t)tap * 262144 + (size_t)(kg * 64 + klane);
#pragma unroll
        for (int q = 0; q < 2; ++q)
            bf[q] = *(const v4i*)&wbL[base + (size_t)q * 8192];
    };

    v4i afA[4], bfA[2], afB[4], bfB[2];
    loadA(0, afA); loadB(0, bfA);

#pragma unroll 1
    for (int it = 0; it < 72; it += 2) {
        loadA(it + 1, afB); loadB(it + 1, bfB);     // prefetch odd iter
#pragma unroll
        for (int q = 0; q < 2; ++q)
#pragma unroll
            for (int m = 0; m < 4; ++m)
                acc[m][q] = __builtin_amdgcn_mfma_i32_16x16x64_i8(
                    afA[m], bfA[q], acc[m][q], 0, 0, 0);
        if (it + 2 < 72) { loadA(it + 2, afA); loadB(it + 2, bfA); }  // prefetch even
#pragma unroll
        for (int q = 0; q < 2; ++q)
#pragma unroll
            for (int m = 0; m < 4; ++m)
                acc[m][q] = __builtin_amdgcn_mfma_i32_16x16x64_i8(
                    afB[m], bfB[q], acc[m][q], 0, 0, 0);
    }

    // epilogue: 2x2 max-pool + f64 htanh -> h5[img][oc][4][4]
#pragma unroll
    for (int m = 0; m < 4; ++m) {
#pragma unroll
        for (int q = 0; q < 2; ++q) {
            const int v01 = max(acc[m][q][0], acc[m][q][1]);
            const int v23 = max(acc[m][q][2], acc[m][q][3]);
            const int p0 = max(v01, __shfl_xor(v01, 32, 64));
            const int p1 = max(v23, __shfl_xor(v23, 32, 64));
            if (kg4 < 2) {
                const int oc = (ntb + q) * 16 + r16;
                const int py = m;
                const int px0 = kg4 * 2;
                const double Av = A[oc], Bv = B[oc];
                const double t0 = fma(Av, (double)p0, Bv);
                const double t1 = fma(Av, (double)p1, Bv);
                float* hp = &h5[(((size_t)img * 512 + oc) * 4 + py) * 4 + px0];
                hp[0] = (float)fmin(1.0, fmax(-1.0, t0));
                hp[1] = (float)fmin(1.0, fmax(-1.0, t1));
            }
        }
    }
}

// ---------------------------------------------------------------------------
// FC (f64 accumulate): out[n,10] = h5[n,8192] @ fcw^T + fcb
// ---------------------------------------------------------------------------
__global__ void fc_kernel(const float* __restrict__ h, const float* __restrict__ fcw,
                          const float* __restrict__ fcb, float* __restrict__ out) {
    const int n = blockIdx.x, t = threadIdx.x;
    double acc[10];
#pragma unroll
    for (int j = 0; j < 10; ++j) acc[j] = 0.0;
    const float* hn = h + (size_t)n * 8192;
    for (int k = t; k < 8192; k += 256) {
        double xv = (double)hn[k];
#pragma unroll
        for (int j = 0; j < 10; ++j) acc[j] += xv * (double)fcw[j * 8192 + k];
    }
    __shared__ double red[10][256];
#pragma unroll
    for (int j = 0; j < 10; ++j) red[j][t] = acc[j];
    __syncthreads();
    for (int r = 128; r > 0; r >>= 1) {
        if (t < r) {
#pragma unroll
            for (int j = 0; j < 10; ++j) red[j][t] += red[j][t + r];
        }
        __syncthreads();
    }
    if (t < 10) out[n * 10 + t] = (float)(red[t][0] + (double)fcb[t]);
}

// ===========================================================================
extern "C" void kernel_launch(void* const* d_in, const int* in_sizes, int n_in,
                              void* d_out, int out_size, void* d_ws, size_t ws_size,
                              hipStream_t stream) {
    const float* X = (const float*)d_in[0];
    BnArgs bn;
    PackArgs pk;
    const float* Wt0 = (const float*)d_in[1];
    for (int i = 0; i < 6; ++i) {
        bn.g[i] = (const float*)d_in[2 + 5 * i];
        bn.b[i] = (const float*)d_in[3 + 5 * i];
        bn.m[i] = (const float*)d_in[4 + 5 * i];
        bn.v[i] = (const float*)d_in[5 + 5 * i];
    }
    for (int i = 0; i < 5; ++i) pk.w[i] = (const float*)d_in[1 + 5 * (i + 1)];
    const float* fcw = (const float*)d_in[31];
    const float* fcb = (const float*)d_in[32];
    float* out = (float*)d_out;

    char* ws = (char*)d_ws;
    size_t off = 0;
    auto alloc = [&](size_t bytes) -> void* {
        void* p = ws + off;
        off = (off + bytes + 255) & ~(size_t)255;
        return p;
    };

    // ---- workspace (~15.1 MB; h5 aliases dead bits0..bits3) ----
    double* scale_all = (double*)alloc(1792 * sizeof(double));
    double* shift_all = (double*)alloc(1792 * sizeof(double));
    double* A_all     = (double*)alloc(1664 * sizeof(double));
    int* tlt_all      = (int*)alloc(1664 * sizeof(int));
    int* tgt_all      = (int*)alloc(1664 * sizeof(int));
    u32* ct_all       = (u32*)alloc(26624 * sizeof(u32));
    signed char* wi8  = (signed char*)alloc(9ull * 512 * 512);   // L5 i8 weights
    const size_t WBN[5] = {128ull * 9 * 2, 256ull * 9 * 2, 256ull * 9 * 4,
                           512ull * 9 * 4, 512ull * 9 * 8};
    for (int i = 0; i < 5; ++i) pk.wbt[i] = (u64*)alloc(WBN[i] * sizeof(u64));
    // padded bit tensors, contiguous (bits4 first, then bits0..bits3)
    u64* bits4 = (u64*)alloc(256ull * 10 * 10 * 8 * sizeof(u64));
    u64* bits0 = (u64*)alloc(256ull * 34 * 34 * 2 * sizeof(u64));
    u64* bits1 = (u64*)alloc(256ull * 18 * 18 * 2 * sizeof(u64));
    u64* bits2 = (u64*)alloc(256ull * 18 * 18 * 4 * sizeof(u64));
    u64* bits3 = (u64*)alloc(256ull * 10 * 10 * 4 * sizeof(u64));
    const size_t bits_u64 =
        256ull * (10 * 10 * 8 + 34 * 34 * 2 + 18 * 18 * 2 + 18 * 18 * 4 + 10 * 10 * 4);
    // h5 (8.4 MB) aliases bits0..bits3 (7.51 MB) + extra tail
    float* h5 = (float*)bits0;
    {
        const size_t h5_bytes = 256ull * 8192 * sizeof(float);
        const size_t have = (size_t)((char*)(bits3 + 256ull * 10 * 10 * 4) - (char*)bits0);
        if (h5_bytes > have) alloc(h5_bytes - have);
    }

    if (off > ws_size) {
        zero_out<<<dim3((out_size + 255) / 256), dim3(256), 0, stream>>>(out, out_size);
        return;
    }

    const int BOF[6] = {0, 128, 256, 512, 768, 1280};
    const int AOF[5] = {0, 128, 384, 640, 1152};
    const int CTO[5] = {0, 2048, 6144, 10240, 18432};

    // ---- preps ----
    bn_prep_all<<<dim3(7), dim3(256), 0, stream>>>(bn, scale_all, shift_all);
    pack_all<<<dim3(1664), dim3(256), 0, stream>>>(pk, scale_all, shift_all,
                                                   A_all, tlt_all, tgt_all, ct_all, wi8);
    zero_u64<<<dim3(2048), dim3(256), 0, stream>>>(bits4, bits_u64);

    // ---- conv0 (padded bits0, LDS weights: measured best) ----
    conv0_pack<<<dim3(4, 256), dim3(256), 0, stream>>>(
        X, Wt0, scale_all + BOF[0], shift_all + BOF[0], bits0);

    // ---- binconv chain L1-L4 (unchanged 558us config) ----
    bconv7<32, 32, 2, 128, 32, true, false, 4><<<dim3(4, 4, 256), dim3(256), 0, stream>>>(
        bits0, pk.wbt[0], nullptr, nullptr, tlt_all + AOF[0], tgt_all + AOF[0],
        ct_all, CTO[0], (u32*)bits1, nullptr);
    bconv7<16, 16, 2, 256, 32, false, false, 4><<<dim3(8, 1, 256), dim3(256), 0, stream>>>(
        bits1, pk.wbt[1], nullptr, nullptr, tlt_all + AOF[1], tgt_all + AOF[1],
        ct_all, CTO[1], (u32*)bits2, nullptr);
    bconv7<16, 16, 4, 256, 32, true, false, 4><<<dim3(8, 1, 256), dim3(256), 0, stream>>>(
        bits2, pk.wbt[2], nullptr, nullptr, tlt_all + AOF[2], tgt_all + AOF[2],
        ct_all, CTO[2], (u32*)bits3, nullptr);
    bconv7<8, 8, 4, 512, 16, false, false, 8><<<dim3(32, 1, 64), dim3(256), 0, stream>>>(
        bits3, pk.wbt[3], nullptr, nullptr, tlt_all + AOF[3], tgt_all + AOF[3],
        ct_all, CTO[3], (u32*)bits4, nullptr);

    // ---- L5 via MFMA i8 (pipelined, oc-split 128/block) ----
    bconv5_mfma<<<dim3(4, 256), dim3(256), 0, stream>>>(
        bits4, wi8, A_all + AOF[4], shift_all + BOF[5], h5);

    // ---- FC ----
    fc_kernel<<<dim3(256), dim3(256), 0, stream>>>(h5, fcw, fcb, out);
}

// Round 12
// 555.393 us; speedup vs baseline: 1.0858x; 1.0858x over previous
//
#include <hip/hip_runtime.h>
#include <cstdint>

#define EPS 1e-5
typedef unsigned long long u64;
typedef unsigned int u32;
typedef unsigned short u16;

struct BnArgs { const float *g[6], *b[6], *m[6], *v[6]; };
struct PackArgs { const float* w[5]; u64* wbt[5]; };

// ---------------------------------------------------------------------------
// Fused BN prep: offsets {0,128,256,512,768,1280}, total 1792.
// ---------------------------------------------------------------------------
__global__ void bn_prep_all(BnArgs p, double* __restrict__ scale_all,
                            double* __restrict__ shift_all) {
    int i = blockIdx.x * 256 + threadIdx.x;
    if (i >= 1792) return;
    int l, base;
    if (i < 128)       { l = 0; base = 0; }
    else if (i < 256)  { l = 1; base = 128; }
    else if (i < 512)  { l = 2; base = 256; }
    else if (i < 768)  { l = 3; base = 512; }
    else if (i < 1280) { l = 4; base = 768; }
    else               { l = 5; base = 1280; }
    const int c = i - base;
    double inv = (double)p.g[l][c] / sqrt((double)p.v[l][c] + EPS);
    scale_all[i] = inv;
    shift_all[i] = (double)p.b[l][c] - (double)p.m[l][c] * inv;
}

__global__ void zero_out(float* __restrict__ out, int n) {
    int i = blockIdx.x * blockDim.x + threadIdx.x;
    if (i < n) out[i] = 0.f;
}

// grid-stride u64 zero (borders of padded bit tensors)
__global__ void zero_u64(u64* __restrict__ p, size_t n) {
    size_t i = (size_t)blockIdx.x * 256 + threadIdx.x;
    const size_t step = (size_t)gridDim.x * 256;
    for (; i < n; i += step) p[i] = 0ull;
}

// ---------------------------------------------------------------------------
// Fused weight pack, tap-major: wbt[(tap*OTOT + o)*W64 + w]. A = alpha*scale.
// Emits the exact edge-correction table AND exact integer thresholds
// (Tlt, Tgt) per filter such that for every integer v:
//   fma(A, (double)v, B) < 0  <=>  (v < Tlt) || (v > Tgt)
// Proof of exactness: fma is a single rounding of the real A*v+B, which is
// monotone in v -> the rounded function is weakly monotone -> a single
// integer crossover; we locate it by evaluating the IDENTICAL fma on a +-4
// window around -B/A (fp error of -B/A << 1 for |t|<6000; crossover is
// within +-2 of t). Sentinels +-2^30 encode constant / one-sided cases.
// ---------------------------------------------------------------------------
__global__ void pack_all(PackArgs pk, const double* __restrict__ scale_all,
                         const double* __restrict__ shift_all,
                         double* __restrict__ A_all,
                         int* __restrict__ tlt_all, int* __restrict__ tgt_all,
                         u32* __restrict__ ct_all) {
    const int ob = blockIdx.x;
    const int t = threadIdx.x;
    int l, base, Cin, bnoff, OTOT, ctoff;
    if (ob < 128)       { l = 0; base = 0;    Cin = 128; bnoff = 128;  OTOT = 128; ctoff = 0; }
    else if (ob < 384)  { l = 1; base = 128;  Cin = 128; bnoff = 256;  OTOT = 256; ctoff = 2048; }
    else if (ob < 640)  { l = 2; base = 384;  Cin = 256; bnoff = 512;  OTOT = 256; ctoff = 6144; }
    else if (ob < 1152) { l = 3; base = 640;  Cin = 256; bnoff = 768;  OTOT = 512; ctoff = 10240; }
    else                { l = 4; base = 1152; Cin = 512; bnoff = 1280; OTOT = 512; ctoff = 18432; }
    const int o = ob - base;
    const float* wo = pk.w[l] + (size_t)o * Cin * 9;

    double s = 0.0;
    for (int k = t; k < Cin * 9; k += 256) s += fabs((double)wo[k]);
    __shared__ double red[256];
    __shared__ u32 stp[9];
    red[t] = s;
    if (t < 9) stp[t] = 0;
    __syncthreads();
    for (int r = 128; r > 0; r >>= 1) {
        if (t < r) red[t] += red[t + r];
        __syncthreads();
    }
    if (t == 0) {
        double alpha = red[0] / (double)(Cin * 9);
        const double dA = alpha * scale_all[bnoff + o];
        const double dB = shift_all[bnoff + o];
        A_all[ob] = dA;
        const int INF = 1 << 30;
        int Tlt, Tgt = INF;
        if (dA > 0.0) {
            const double tt = -dB / dA;
            if (!(fabs(tt) < 6000.0)) {
                Tlt = (dB < 0.0) ? INF : -INF;   // constant over |v|<=4608
            } else {
                int v0 = (int)floor(tt) - 4;
                int c = INF;                      // first v with fma >= 0
                for (int v = v0; v < v0 + 9; ++v)
                    if (fma(dA, (double)v, dB) >= 0.0) { c = v; break; }
                Tlt = c;                          // bit <=> v < c
            }
        } else if (dA < 0.0) {
            const double tt = -dB / dA;
            if (!(fabs(tt) < 6000.0)) {
                Tlt = (dB < 0.0) ? INF : -INF;
            } else {
                int v0 = (int)floor(tt) - 4;
                int c = INF;                      // first v with fma < 0
                for (int v = v0; v < v0 + 9; ++v)
                    if (fma(dA, (double)v, dB) < 0.0) { c = v; break; }
                Tlt = -INF;
                Tgt = (c == INF) ? INF : (c - 1); // bit <=> v > c-1
            }
        } else {
            Tlt = (dB < 0.0) ? INF : -INF;        // constant
        }
        tlt_all[ob] = Tlt;
        tgt_all[ob] = Tgt;
    }

    const int W64 = Cin / 64;
    u64* wbt = pk.wbt[l];
    for (int e = t; e < 9 * W64; e += 256) {
        int tap = e / W64, word = e % W64;
        u64 bits = 0;
        for (int j = 0; j < 64; ++j) {
            int c = word * 64 + j;
            if (wo[c * 9 + tap] < 0.f) bits |= (1ull << j);
        }
        wbt[((size_t)tap * OTOT + o) * W64 + word] = bits;
        atomicAdd(&stp[tap], (u32)__popcll(bits));
    }
    __syncthreads();

    if (t < 16) {
        const int pat = t;
        int nv = 0;
        u32 cor = 0;
#pragma unroll
        for (int tap = 0; tap < 9; ++tap) {
            const int dy = tap / 3, dx = tap % 3;
            const bool inv = ((pat & 1) && dy == 0) || ((pat & 2) && dy == 2) ||
                             ((pat & 4) && dx == 0) || ((pat & 8) && dx == 2);
            if (inv) cor += stp[tap]; else nv++;
        }
        ct_all[ctoff + pat * OTOT + o] = (u32)(nv * 64 * W64) + 2u * cor;
    }
}

// ---------------------------------------------------------------------------
// conv0 (f64 exact), lane = pixel -> PADDED bits0 [n][34][34][2].
// (round-3/7 measured-best form: LDS-staged weights)
// ---------------------------------------------------------------------------
__global__ __launch_bounds__(256) void conv0_pack(
        const float* __restrict__ x, const float* __restrict__ w0,
        const double* __restrict__ scale, const double* __restrict__ shift,
        u64* __restrict__ bits0) {
    __shared__ double wlds[128 * 27];
    __shared__ double sc[128], sh[128];
    const int tid = threadIdx.x;
    for (int e = tid; e < 128 * 27; e += 256) wlds[e] = (double)w0[e];
    for (int e = tid; e < 128; e += 256) { sc[e] = scale[e]; sh[e] = shift[e]; }
    __syncthreads();

    const int n = blockIdx.y;
    const int p = blockIdx.x * 256 + tid;
    const int y = p >> 5, xx = p & 31;
    const float* xn = x + (size_t)n * 3 * 32 * 32;

    double win[27];
#pragma unroll
    for (int c = 0; c < 3; ++c)
#pragma unroll
        for (int dy = 0; dy < 3; ++dy)
#pragma unroll
            for (int dx = 0; dx < 3; ++dx) {
                const int yy = y + dy - 1, xs = xx + dx - 1;
                const bool ok = (yy >= 0 && yy < 32 && xs >= 0 && xs < 32);
                win[(c * 3 + dy) * 3 + dx] = ok ? (double)xn[(c * 32 + yy) * 32 + xs] : 0.0;
            }

    u64* op = bits0 + (((size_t)n * 34 + (y + 1)) * 34 + (xx + 1)) * 2;
#pragma unroll
    for (int og = 0; og < 2; ++og) {
        u64 word = 0;
#pragma unroll 2
        for (int j = 0; j < 64; ++j) {
            const int o = og * 64 + j;
            const double* wo = &wlds[o * 27];
            double acc = 0.0;
#pragma unroll
            for (int k = 0; k < 27; ++k) acc = fma(wo[k], win[k], acc);
            const double val = acc * sc[o] + sh[o];
            word |= (u64)(val < 0.0) << j;
        }
        op[og] = word;
    }
}

// ---------------------------------------------------------------------------
// bconv7: padded input (zero ring), xor+__popcll hot loop (measured best).
// Weights wave-uniform -> scalar s_load path. Tiny LDS (ct table only).
// Non-LAST epilogue: exact integer thresholds (bit = (v<Tlt)|(v>Tgt));
// LAST (L5): f64 htanh path. OPW=16 layers write u16 half-words.
// POOL: 2x2 int max via shfl_xor(1), shfl_xor(W).
// ---------------------------------------------------------------------------
template<int H, int W, int W64, int OTOT, int OPW, bool POOL, bool LAST, int MINW>
__global__ __launch_bounds__(256, MINW) void bconv7(
        const u64* __restrict__ in_bits, const u64* __restrict__ wbt,
        const double* __restrict__ A, const double* __restrict__ B,
        const int* __restrict__ tlt, const int* __restrict__ tgt,
        const u32* __restrict__ ct_all, int ctoff,
        u32* __restrict__ out_bits, float* __restrict__ h5) {
    const int tid = threadIdx.x;
    const int wave = tid >> 6, lane = tid & 63;
    constexpr int WPI = (H * W) / 64;   // 64-pixel slices per image
    const int img = (WPI >= 4) ? blockIdx.z : (blockIdx.z * 4 + wave);
    const int wii = (WPI >= 4) ? (blockIdx.y * 4 + wave) : 0;
    const int y = wii * (64 / W) + lane / W;
    const int x = lane % W;
    const int obase = blockIdx.x * OPW;

    // tiny LDS: edge-correction table only (stride OPW+1: conflict-free)
    __shared__ u32 ctl[16 * (OPW + 1)];
    for (int e = tid; e < 16 * OPW; e += 256) {
        const int pat = e / OPW, oc = e % OPW;
        ctl[pat * (OPW + 1) + oc] = ct_all[ctoff + pat * OTOT + obase + oc];
    }
    __syncthreads();

    constexpr int RC = W + 2;
    const u64* ib = in_bits + (size_t)img * (H + 2) * RC * W64;

    int acc[OPW];
#pragma unroll
    for (int oc = 0; oc < OPW; ++oc) acc[oc] = 0;

#pragma unroll 1
    for (int dy = 0; dy < 3; ++dy) {
#pragma unroll 1
        for (int dx = 0; dx < 3; ++dx) {
            // per-lane activation words (vector loads, L2-resident)
            const u64* q = ib + ((size_t)(y + dy) * RC + (x + dx)) * W64;
            u64 wn[W64];
#pragma unroll
            for (int k = 0; k < W64; ++k) wn[k] = q[k];
            // wave-uniform weight base -> scalar loads (s_load, K$)
            const u64* wt = wbt + (size_t)((dy * 3 + dx) * OTOT + obase) * W64;
#pragma unroll
            for (int oc = 0; oc < OPW; ++oc) {
#pragma unroll
                for (int k = 0; k < W64; ++k)
                    acc[oc] += (int)__popcll(wn[k] ^ wt[oc * W64 + k]);
            }
        }
    }

    const int pat = (y == 0 ? 1 : 0) | (y == H - 1 ? 2 : 0) |
                    (x == 0 ? 4 : 0) | (x == W - 1 ? 8 : 0);
    const int ctbase = pat * (OPW + 1);
    constexpr int Hp = POOL ? H / 2 : H, Wp = POOL ? W / 2 : W;
    const bool writer = (!POOL) || (((lane & 1) == 0) && ((lane & W) == 0));
    const int py = POOL ? (y >> 1) : y, px = POOL ? (x >> 1) : x;

    u32 cur = 0;
#pragma unroll
    for (int oc = 0; oc < OPW; ++oc) {
        int v = (int)ctl[ctbase + oc] - 2 * acc[oc];
        if (POOL) {
            int v2 = max(v, __shfl_xor(v, 1, 64));
            v = max(v2, __shfl_xor(v2, W, 64));
        }
        if (LAST) {
            // f64 htanh path (A,B wave-uniform -> scalar f64 loads)
            const double t = fma(A[obase + oc], (double)v, B[obase + oc]);
            const double hcl = fmin(1.0, fmax(-1.0, t));
            if (writer)
                h5[(((size_t)img * OTOT + obase + oc) * Hp + py) * Wp + px] = (float)hcl;
        } else {
            // exact integer-threshold sign test (wave-uniform scalars)
            const bool bit = (v < tlt[obase + oc]) | (v > tgt[obase + oc]);
            cur |= (u32)bit << oc;
        }
    }
    if (!LAST && writer) {
        const size_t wordIdx =
            (((size_t)img * (Hp + 2) + (py + 1)) * (Wp + 2) + (px + 1)) * (OTOT / 32)
            + (obase >> 5);
        if (OPW == 32) {
            out_bits[wordIdx] = cur;
        } else {
            // OPW==16: two obase blocks share one u32 word -> disjoint u16 halves
            u16* o16 = (u16*)out_bits;
            o16[wordIdx * 2 + ((obase >> 4) & 1)] = (u16)cur;
        }
    }
}

// ---------------------------------------------------------------------------
// FC (f64 accumulate): out[n,10] = h5[n,8192] @ fcw^T + fcb
// ---------------------------------------------------------------------------
__global__ void fc_kernel(const float* __restrict__ h, const float* __restrict__ fcw,
                          const float* __restrict__ fcb, float* __restrict__ out) {
    const int n = blockIdx.x, t = threadIdx.x;
    double acc[10];
#pragma unroll
    for (int j = 0; j < 10; ++j) acc[j] = 0.0;
    const float* hn = h + (size_t)n * 8192;
    for (int k = t; k < 8192; k += 256) {
        double xv = (double)hn[k];
#pragma unroll
        for (int j = 0; j < 10; ++j) acc[j] += xv * (double)fcw[j * 8192 + k];
    }
    __shared__ double red[10][256];
#pragma unroll
    for (int j = 0; j < 10; ++j) red[j][t] = acc[j];
    __syncthreads();
    for (int r = 128; r > 0; r >>= 1) {
        if (t < r) {
#pragma unroll
            for (int j = 0; j < 10; ++j) red[j][t] += red[j][t + r];
        }
        __syncthreads();
    }
    if (t < 10) out[n * 10 + t] = (float)(red[t][0] + (double)fcb[t]);
}

// ===========================================================================
extern "C" void kernel_launch(void* const* d_in, const int* in_sizes, int n_in,
                              void* d_out, int out_size, void* d_ws, size_t ws_size,
                              hipStream_t stream) {
    const float* X = (const float*)d_in[0];
    BnArgs bn;
    PackArgs pk;
    const float* Wt0 = (const float*)d_in[1];
    for (int i = 0; i < 6; ++i) {
        bn.g[i] = (const float*)d_in[2 + 5 * i];
        bn.b[i] = (const float*)d_in[3 + 5 * i];
        bn.m[i] = (const float*)d_in[4 + 5 * i];
        bn.v[i] = (const float*)d_in[5 + 5 * i];
    }
    for (int i = 0; i < 5; ++i) pk.w[i] = (const float*)d_in[1 + 5 * (i + 1)];
    const float* fcw = (const float*)d_in[31];
    const float* fcb = (const float*)d_in[32];
    float* out = (float*)d_out;

    char* ws = (char*)d_ws;
    size_t off = 0;
    auto alloc = [&](size_t bytes) -> void* {
        void* p = ws + off;
        off = (off + bytes + 255) & ~(size_t)255;
        return p;
    };

    // ---- workspace (~10.8 MB; h5 aliases dead bits0..bits3) ----
    double* scale_all = (double*)alloc(1792 * sizeof(double));
    double* shift_all = (double*)alloc(1792 * sizeof(double));
    double* A_all     = (double*)alloc(1664 * sizeof(double));
    int* tlt_all      = (int*)alloc(1664 * sizeof(int));
    int* tgt_all      = (int*)alloc(1664 * sizeof(int));
    u32* ct_all       = (u32*)alloc(26624 * sizeof(u32));
    const size_t WBN[5] = {128ull * 9 * 2, 256ull * 9 * 2, 256ull * 9 * 4,
                           512ull * 9 * 4, 512ull * 9 * 8};
    for (int i = 0; i < 5; ++i) pk.wbt[i] = (u64*)alloc(WBN[i] * sizeof(u64));
    // padded bit tensors, contiguous (bits4 first, then bits0..bits3)
    u64* bits4 = (u64*)alloc(256ull * 10 * 10 * 8 * sizeof(u64));
    u64* bits0 = (u64*)alloc(256ull * 34 * 34 * 2 * sizeof(u64));
    u64* bits1 = (u64*)alloc(256ull * 18 * 18 * 2 * sizeof(u64));
    u64* bits2 = (u64*)alloc(256ull * 18 * 18 * 4 * sizeof(u64));
    u64* bits3 = (u64*)alloc(256ull * 10 * 10 * 4 * sizeof(u64));
    const size_t bits_u64 =
        256ull * (10 * 10 * 8 + 34 * 34 * 2 + 18 * 18 * 2 + 18 * 18 * 4 + 10 * 10 * 4);
    // h5 (8.4 MB) aliases bits0..bits3 (7.51 MB) + extra tail
    float* h5 = (float*)bits0;
    {
        const size_t h5_bytes = 256ull * 8192 * sizeof(float);
        const size_t have = (size_t)((char*)(bits3 + 256ull * 10 * 10 * 4) - (char*)bits0);
        if (h5_bytes > have) alloc(h5_bytes - have);
    }

    if (off > ws_size) {
        zero_out<<<dim3((out_size + 255) / 256), dim3(256), 0, stream>>>(out, out_size);
        return;
    }

    const int BOF[6] = {0, 128, 256, 512, 768, 1280};
    const int AOF[5] = {0, 128, 384, 640, 1152};
    const int CTO[5] = {0, 2048, 6144, 10240, 18432};

    // ---- preps ----
    bn_prep_all<<<dim3(7), dim3(256), 0, stream>>>(bn, scale_all, shift_all);
    pack_all<<<dim3(1664), dim3(256), 0, stream>>>(pk, scale_all, shift_all,
                                                   A_all, tlt_all, tgt_all, ct_all);
    zero_u64<<<dim3(2048), dim3(256), 0, stream>>>(bits4, bits_u64);

    // ---- conv0 (padded bits0, LDS weights: measured best) ----
    conv0_pack<<<dim3(4, 256), dim3(256), 0, stream>>>(
        X, Wt0, scale_all + BOF[0], shift_all + BOF[0], bits0);

    // ---- binconv chain (scalar weights + integer-threshold epilogue) ----
    // L1: 128->128, 32x32, pool  (4096 blocks)
    bconv7<32, 32, 2, 128, 32, true, false, 4><<<dim3(4, 4, 256), dim3(256), 0, stream>>>(
        bits0, pk.wbt[0], nullptr, nullptr, tlt_all + AOF[0], tgt_all + AOF[0],
        ct_all, CTO[0], (u32*)bits1, nullptr);
    // L2: 128->256, 16x16  (2048 blocks)
    bconv7<16, 16, 2, 256, 32, false, false, 4><<<dim3(8, 1, 256), dim3(256), 0, stream>>>(
        bits1, pk.wbt[1], nullptr, nullptr, tlt_all + AOF[1], tgt_all + AOF[1],
        ct_all, CTO[1], (u32*)bits2, nullptr);
    // L3: 256->256, 16x16, pool  (2048 blocks)
    bconv7<16, 16, 4, 256, 32, true, false, 4><<<dim3(8, 1, 256), dim3(256), 0, stream>>>(
        bits2, pk.wbt[2], nullptr, nullptr, tlt_all + AOF[2], tgt_all + AOF[2],
        ct_all, CTO[2], (u32*)bits3, nullptr);
    // L4: 256->512, 8x8  (OPW=16 -> 2048 blocks, u16 half-word writes)
    bconv7<8, 8, 4, 512, 16, false, false, 8><<<dim3(32, 1, 64), dim3(256), 0, stream>>>(
        bits3, pk.wbt[3], nullptr, nullptr, tlt_all + AOF[3], tgt_all + AOF[3],
        ct_all, CTO[3], (u32*)bits4, nullptr);
    // L5: 512->512, 8x8, pool -> h5  (f64 htanh epilogue)
    bconv7<8, 8, 8, 512, 16, true, true, 8><<<dim3(32, 1, 64), dim3(256), 0, stream>>>(
        bits4, pk.wbt[4], A_all + AOF[4], shift_all + BOF[5], nullptr, nullptr,
        ct_all, CTO[4], nullptr, h5);

    // ---- FC ----
    fc_kernel<<<dim3(256), dim3(256), 0, stream>>>(h5, fcw, fcb, out);
}